// Round 1
// baseline (562.245 us; speedup 1.0000x reference)
//
#include <hip/hip_runtime.h>
#include <cstdint>
#include <cstddef>

// ---------------------------------------------------------------------------
// GCN 2-layer: out = GCNConv2( relu( GCNConv1(x) ) )
// Strategy:
//   1. Build degree + CSR (grouped by dst) once per call; reused by both layers.
//   2. h1 = x @ W1            (dense, memory-bound)
//   3. g1 = relu(prop(h1)+b1) (pull-style gather, wave-per-node, no atomics on floats)
//   4. h2 = g1 @ W2
//   5. out = prop(h2) + b2
// Edge dtype (int32 vs int64) is detected on-device: int64 high words of
// values < 2^31 are all zero; int32 random values are not.
// ---------------------------------------------------------------------------

__global__ void k_init(int* __restrict__ cnt, int N, int* __restrict__ flag) {
  int i = blockIdx.x * blockDim.x + threadIdx.x;
  if (i < N) cnt[i] = 0;
  if (i == 0) *flag = 1;  // assume int64 until proven otherwise
}

__global__ void k_detect(const int* __restrict__ e32, int twoE, int* __restrict__ flag) {
  int i = blockIdx.x * blockDim.x + threadIdx.x;
  if (i < 1024) {
    int idx = 2 * i + 1;  // odd int32 slots = high words if buffer is int64
    if (idx < twoE && e32[idx] != 0) atomicAnd(flag, 0);  // int32 data
  }
}

__device__ __forceinline__ int load_edge(const int* e32, int idx, int is64) {
  if (is64) return (int)((const long long*)e32)[idx];
  return e32[idx];
}

__global__ void k_hist(const int* __restrict__ e32, int E, int* __restrict__ cnt,
                       const int* __restrict__ flag) {
  int i = blockIdx.x * blockDim.x + threadIdx.x;
  if (i >= E) return;
  int is64 = *flag;
  int d = load_edge(e32, E + i, is64);
  atomicAdd(&cnt[d], 1);
}

__global__ void k_dinv(const int* __restrict__ cnt, float* __restrict__ dinv, int N) {
  int i = blockIdx.x * blockDim.x + threadIdx.x;
  if (i < N) dinv[i] = rsqrtf((float)cnt[i] + 1.0f);  // +1 = self-loop
}

// ---- exclusive scan of cnt -> rowptr (3-pass, 1024 elems/block) ----
__global__ void k_scan1(const int* __restrict__ cnt, int N, int* __restrict__ rowptr,
                        int* __restrict__ partial) {
  __shared__ int sh[256];
  const int t = threadIdx.x;
  const int base = blockIdx.x * 1024 + t * 4;
  int v0 = (base + 0 < N) ? cnt[base + 0] : 0;
  int v1 = (base + 1 < N) ? cnt[base + 1] : 0;
  int v2 = (base + 2 < N) ? cnt[base + 2] : 0;
  int v3 = (base + 3 < N) ? cnt[base + 3] : 0;
  int s = v0 + v1 + v2 + v3;
  sh[t] = s;
  __syncthreads();
  for (int off = 1; off < 256; off <<= 1) {
    int add = (t >= off) ? sh[t - off] : 0;
    __syncthreads();
    sh[t] += add;
    __syncthreads();
  }
  int excl = sh[t] - s;
  if (base + 0 < N) rowptr[base + 0] = excl;
  if (base + 1 < N) rowptr[base + 1] = excl + v0;
  if (base + 2 < N) rowptr[base + 2] = excl + v0 + v1;
  if (base + 3 < N) rowptr[base + 3] = excl + v0 + v1 + v2;
  if (t == 255) partial[blockIdx.x] = sh[255];
}

__global__ void k_scan2(int* __restrict__ partial, int NB) {
  __shared__ int sh[256];
  int t = threadIdx.x;
  int v = (t < NB) ? partial[t] : 0;
  sh[t] = v;
  __syncthreads();
  for (int off = 1; off < 256; off <<= 1) {
    int add = (t >= off) ? sh[t - off] : 0;
    __syncthreads();
    sh[t] += add;
    __syncthreads();
  }
  if (t < NB) partial[t] = sh[t] - v;  // exclusive
}

__global__ void k_scan3(int* __restrict__ rowptr, int* __restrict__ cursor,
                        const int* __restrict__ partial, int N, int E) {
  int i = blockIdx.x * blockDim.x + threadIdx.x;
  if (i < N) {
    int r = rowptr[i] + partial[i >> 10];
    rowptr[i] = r;
    cursor[i] = r;
  }
  if (i == 0) rowptr[N] = E;
}

__global__ void k_fill(const int* __restrict__ e32, int E, const float* __restrict__ dinv,
                       int* __restrict__ cursor, int2* __restrict__ rec,
                       const int* __restrict__ flag) {
  int i = blockIdx.x * blockDim.x + threadIdx.x;
  if (i >= E) return;
  int is64 = *flag;
  int s = load_edge(e32, i, is64);
  int d = load_edge(e32, E + i, is64);
  int pos = atomicAdd(&cursor[d], 1);
  float w = dinv[s] * dinv[d];
  rec[pos] = make_int2(s, __float_as_int(w));
}

// ---- dense transform H[N][COUT] = X[N][CIN] @ W[CIN][COUT] ----
// 64 nodes per block; thread owns one column for RPG rows (register tile).
template <int CIN, int COUT>
__global__ void k_gemm(const float* __restrict__ X, const float* __restrict__ W,
                       float* __restrict__ H, int N) {
  constexpr int GROUPS = 256 / COUT;
  constexpr int RPG = 64 / GROUPS;
  const int c = threadIdx.x % COUT;
  const int g = threadIdx.x / COUT;
  const int nb = blockIdx.x * 64 + g * RPG;
  const float4* X4 = (const float4*)X;
  float acc[RPG];
#pragma unroll
  for (int r = 0; r < RPG; ++r) acc[r] = 0.f;
#pragma unroll 4
  for (int k4 = 0; k4 < CIN / 4; ++k4) {
    float w0 = W[(k4 * 4 + 0) * COUT + c];
    float w1 = W[(k4 * 4 + 1) * COUT + c];
    float w2 = W[(k4 * 4 + 2) * COUT + c];
    float w3 = W[(k4 * 4 + 3) * COUT + c];
#pragma unroll
    for (int r = 0; r < RPG; ++r) {
      int n = nb + r;
      if (n > N - 1) n = N - 1;  // clamp: duplicate reads, harmless
      float4 x = X4[(size_t)n * (CIN / 4) + k4];
      acc[r] = fmaf(x.x, w0, acc[r]);
      acc[r] = fmaf(x.y, w1, acc[r]);
      acc[r] = fmaf(x.z, w2, acc[r]);
      acc[r] = fmaf(x.w, w3, acc[r]);
    }
  }
#pragma unroll
  for (int r = 0; r < RPG; ++r) {
    int n = nb + r;
    if (n < N) H[(size_t)n * COUT + c] = acc[r];
  }
}

// ---- pull-style propagation: one wave per destination node ----
// C==64: lane = feature. C==32: lane&31 = feature, half-waves split edge list.
template <int C, bool RELU>
__global__ void k_prop(const float* __restrict__ H, const int2* __restrict__ rec,
                       const int* __restrict__ rowptr, const float* __restrict__ dinv,
                       const float* __restrict__ bias, float* __restrict__ out, int N) {
  const int gid = blockIdx.x * blockDim.x + threadIdx.x;
  const int n = gid >> 6;
  const int lane = threadIdx.x & 63;
  if (n >= N) return;
  const int c = lane & (C - 1);
  const float di = dinv[n];
  const int beg = rowptr[n];
  const int end = rowptr[n + 1];
  float acc = 0.f;
  if (C == 64) {
    acc = H[(size_t)n * C + c] * (di * di);  // self-loop term
    for (int e = beg; e < end; ++e) {
      int2 sw = rec[e];
      acc = fmaf(__int_as_float(sw.y), H[(size_t)sw.x * C + c], acc);
    }
  } else {
    const int half = lane >> 5;
    if (half == 0) acc = H[(size_t)n * C + c] * (di * di);
    for (int e = beg + half; e < end; e += 2) {
      int2 sw = rec[e];
      acc = fmaf(__int_as_float(sw.y), H[(size_t)sw.x * C + c], acc);
    }
    acc += __shfl_xor(acc, 32);  // combine half-wave partial sums
    if (half) return;            // lower half writes
  }
  acc += bias[c];
  if (RELU) acc = fmaxf(acc, 0.f);
  out[(size_t)n * C + c] = acc;
}

extern "C" void kernel_launch(void* const* d_in, const int* in_sizes, int n_in,
                              void* d_out, int out_size, void* d_ws, size_t ws_size,
                              hipStream_t stream) {
  (void)n_in; (void)out_size; (void)ws_size;
  const float* x = (const float*)d_in[0];
  const int* edges = (const int*)d_in[1];
  const float* W1 = (const float*)d_in[2];
  const float* b1 = (const float*)d_in[3];
  const float* W2 = (const float*)d_in[4];
  const float* b2 = (const float*)d_in[5];

  const int N = in_sizes[0] / 64;
  const int E = in_sizes[1] / 2;

  // workspace carve-up (256B aligned)
  char* ws = (char*)d_ws;
  size_t off = 0;
  auto carve = [&](size_t bytes) -> void* {
    void* p = ws + off;
    off = (off + bytes + 255) & ~(size_t)255;
    return p;
  };
  int* flag     = (int*)carve(4);
  int* cnt      = (int*)carve((size_t)N * 4);
  int* rowptr   = (int*)carve((size_t)(N + 1) * 4);
  int* cursor   = (int*)carve((size_t)N * 4);
  float* dinv   = (float*)carve((size_t)N * 4);
  int* partial  = (int*)carve(1024);
  int2* rec     = (int2*)carve((size_t)E * 8);
  float* h1     = (float*)carve((size_t)N * 64 * 4);
  float* g1     = (float*)carve((size_t)N * 64 * 4);
  float* h2     = (float*)carve((size_t)N * 32 * 4);

  const int nbN = (N + 255) / 256;
  const int nbE = (E + 255) / 256;
  const int NB = (N + 1023) / 1024;  // must be <= 256 (N <= 262144)

  k_init<<<nbN, 256, 0, stream>>>(cnt, N, flag);
  k_detect<<<4, 256, 0, stream>>>(edges, 2 * E, flag);
  k_hist<<<nbE, 256, 0, stream>>>(edges, E, cnt, flag);
  k_dinv<<<nbN, 256, 0, stream>>>(cnt, dinv, N);
  k_scan1<<<NB, 256, 0, stream>>>(cnt, N, rowptr, partial);
  k_scan2<<<1, 256, 0, stream>>>(partial, NB);
  k_scan3<<<nbN, 256, 0, stream>>>(rowptr, cursor, partial, N, E);
  k_fill<<<nbE, 256, 0, stream>>>(edges, E, dinv, cursor, rec, flag);

  k_gemm<64, 64><<<(N + 63) / 64, 256, 0, stream>>>(x, W1, h1, N);
  k_prop<64, true><<<(N + 3) / 4, 256, 0, stream>>>(h1, rec, rowptr, dinv, b1, g1, N);
  k_gemm<64, 32><<<(N + 63) / 64, 256, 0, stream>>>(g1, W2, h2, N);
  k_prop<32, false><<<(N + 3) / 4, 256, 0, stream>>>(h2, rec, rowptr, dinv, b2,
                                                     (float*)d_out, N);
}